// Round 5
// baseline (1147.981 us; speedup 1.0000x reference)
//
#include <hip/hip_runtime.h>
#include <math.h>

// Problem constants (B=2, H=16, L=2048, D=128, fp32 in/out, int32 mask)
constexpr int Bc_ = 2;
constexpr int Hc_ = 16;
constexpr int Lc_ = 2048;
constexpr int Dc_ = 128;
constexpr int BR  = 64;   // Q rows per block (4 waves x 16)
constexpr int BC  = 32;   // K rows per tile
constexpr float SCALE = 0.08838834764831845f;  // 1/sqrt(128)
constexpr float NEGV  = -10000.0f;

typedef __attribute__((ext_vector_type(8))) short          bf16x8;
typedef __attribute__((ext_vector_type(8))) unsigned short u16x8;
typedef __attribute__((ext_vector_type(4))) float          f32x4;

// fp32 -> bf16 round-to-nearest-even
__device__ __forceinline__ unsigned short f2bf(float f) {
  unsigned u = __builtin_bit_cast(unsigned, f);
  return (unsigned short)((u + 0x7fffu + ((u >> 16) & 1u)) >> 16);
}

// Workgroup barrier that does NOT drain vmcnt (unlike __syncthreads).
// LDS visibility needs lgkmcnt(0) only; register-prefetch global loads
// stay in flight across the barrier.
__device__ __forceinline__ void barrier_lgkm() {
  asm volatile("s_waitcnt lgkmcnt(0)\n\ts_barrier" ::: "memory");
}

constexpr int KS_STRIDE = 136;  // K tile rows (+8 pad)
constexpr int VT_STRIDE = 72;   // V^T rows, 16B-aligned
constexpr int PS_STRIDE = 40;   // P staging rows

// ---- load 8 mask scalars for this thread's 4 rows x 2 cols at tile kbn ----
#define MASK_LOAD(MN, KBN)                                                  \
  {                                                                         \
    const int* mp = mbase_g + (KBN);                                        \
    MN##0 = mp[0 * Lc_];      MN##1 = mp[0 * Lc_ + 16];                     \
    MN##2 = mp[1 * Lc_];      MN##3 = mp[1 * Lc_ + 16];                     \
    MN##4 = mp[2 * Lc_];      MN##5 = mp[2 * Lc_ + 16];                     \
    MN##6 = mp[3 * Lc_];      MN##7 = mp[3 * Lc_ + 16];                     \
  }

// ---- softmax for one Q-row R, masks as named scalar registers ----
#define SOFTMAX_ROW(R, M0, M1)                                              \
  {                                                                         \
    float s0 = ((M0) == 0) ? NEGV : sblk[0][R];                             \
    float s1 = ((M1) == 0) ? NEGV : sblk[1][R];                             \
    float rowmax = fmaxf(s0, s1);                                           \
    rowmax = fmaxf(rowmax, __shfl_xor(rowmax, 1));                          \
    rowmax = fmaxf(rowmax, __shfl_xor(rowmax, 2));                          \
    rowmax = fmaxf(rowmax, __shfl_xor(rowmax, 4));                          \
    rowmax = fmaxf(rowmax, __shfl_xor(rowmax, 8));                          \
    const float mnew  = fmaxf(mstate[R], rowmax);                           \
    const float alpha = __expf(mstate[R] - mnew);                           \
    const float p0 = __expf(s0 - mnew);                                     \
    const float p1 = __expf(s1 - mnew);                                     \
    float rs = p0 + p1;                                                     \
    rs += __shfl_xor(rs, 1);                                                \
    rs += __shfl_xor(rs, 2);                                                \
    rs += __shfl_xor(rs, 4);                                                \
    rs += __shfl_xor(rs, 8);                                                \
    lstate[R] = lstate[R] * alpha + rs;                                     \
    mstate[R] = mnew;                                                       \
    acc[0][R] *= alpha; acc[1][R] *= alpha; acc[2][R] *= alpha;             \
    acc[3][R] *= alpha; acc[4][R] *= alpha; acc[5][R] *= alpha;             \
    acc[6][R] *= alpha; acc[7][R] *= alpha;                                 \
    unsigned short* prow = &Ps[(w * 16 + quad * 4 + (R)) * PS_STRIDE];      \
    prow[t16]      = f2bf(p0);                                              \
    prow[16 + t16] = f2bf(p1);                                              \
  }

// ---- one K-tile iteration. MC = this tile's mask buffer (consumed in
// softmax, then REFILLED with tile t+4's mask -> ~4 tiles of latency cover
// for the 536 MB uncacheable mask stream; K/V stay distance-1, L2-resident).
#define TILE_BODY(KB, MC)                                                   \
  {                                                                         \
    /* 1. stage current K regs -> LDS (bf16, row-major) */                  \
    {                                                                       \
      u16x8 p0, p1;                                                         \
      p0[0]=f2bf(kr[0][0]); p0[1]=f2bf(kr[0][1]); p0[2]=f2bf(kr[0][2]); p0[3]=f2bf(kr[0][3]); \
      p0[4]=f2bf(kr[1][0]); p0[5]=f2bf(kr[1][1]); p0[6]=f2bf(kr[1][2]); p0[7]=f2bf(kr[1][3]); \
      p1[0]=f2bf(kr[2][0]); p1[1]=f2bf(kr[2][1]); p1[2]=f2bf(kr[2][2]); p1[3]=f2bf(kr[2][3]); \
      p1[4]=f2bf(kr[3][0]); p1[5]=f2bf(kr[3][1]); p1[6]=f2bf(kr[3][2]); p1[7]=f2bf(kr[3][3]); \
      *(u16x8*)&Ks[krow * KS_STRIDE + kcg * 16]     = p0;                   \
      *(u16x8*)&Ks[krow * KS_STRIDE + kcg * 16 + 8] = p1;                   \
    }                                                                       \
    /* stage current V regs -> LDS transposed */                            \
    _Pragma("unroll")                                                       \
    for (int c4 = 0; c4 < 4; ++c4) {                                        \
      Vt[(vcg * 16 + c4 * 4 + 0) * VT_STRIDE + vrow] = f2bf(vr[c4][0]);     \
      Vt[(vcg * 16 + c4 * 4 + 1) * VT_STRIDE + vrow] = f2bf(vr[c4][1]);     \
      Vt[(vcg * 16 + c4 * 4 + 2) * VT_STRIDE + vrow] = f2bf(vr[c4][2]);     \
      Vt[(vcg * 16 + c4 * 4 + 3) * VT_STRIDE + vrow] = f2bf(vr[c4][3]);     \
    }                                                                       \
    /* 2. issue next-tile K/V loads (stay in flight across barrier) */      \
    {                                                                       \
      const int kbn = ((KB) + BC) & (Lc_ - 1);                              \
      const float* kp = kbase_g + (size_t)kbn * Dc_;                        \
      const float* vp = vbase_g + (size_t)kbn * Dc_;                        \
      kr[0] = *(const f32x4*)(kp + 0);  kr[1] = *(const f32x4*)(kp + 4);    \
      kr[2] = *(const f32x4*)(kp + 8);  kr[3] = *(const f32x4*)(kp + 12);   \
      vr[0] = *(const f32x4*)(vp + 0);  vr[1] = *(const f32x4*)(vp + 4);    \
      vr[2] = *(const f32x4*)(vp + 8);  vr[3] = *(const f32x4*)(vp + 12);   \
    }                                                                       \
    /* 3. barrier (lgkm only) */                                            \
    barrier_lgkm();                                                         \
    /* 4. S = (Q*scale) K^T */                                              \
    f32x4 sblk[2];                                                          \
    _Pragma("unroll")                                                       \
    for (int blk = 0; blk < 2; ++blk) {                                     \
      f32x4 s = (f32x4)0.0f;                                                \
      const unsigned short* kb_l = &Ks[(blk * 16 + t16) * KS_STRIDE + quad * 8]; \
      _Pragma("unroll")                                                     \
      for (int st = 0; st < 4; ++st) {                                      \
        bf16x8 bf = *(const bf16x8*)(kb_l + st * 32);                       \
        s = __builtin_amdgcn_mfma_f32_16x16x32_bf16(qf[st], bf, s, 0, 0, 0);\
      }                                                                     \
      sblk[blk] = s;                                                        \
    }                                                                       \
    /* 5. mask + online softmax (masks in registers, loaded 4 tiles ago) */ \
    SOFTMAX_ROW(0, MC##0, MC##1)                                            \
    SOFTMAX_ROW(1, MC##2, MC##3)                                            \
    SOFTMAX_ROW(2, MC##4, MC##5)                                            \
    SOFTMAX_ROW(3, MC##6, MC##7)                                            \
    /* 5.5 refill this mask buffer for tile t+4 (distance-4 prefetch) */    \
    MASK_LOAD(MC, ((KB) + 4 * BC) & (Lc_ - 1))                              \
    /* 6. O += P * V */                                                     \
    {                                                                       \
      const bf16x8 pf = *(const bf16x8*)&Ps[(w * 16 + t16) * PS_STRIDE + quad * 8]; \
      _Pragma("unroll")                                                     \
      for (int nb = 0; nb < 8; ++nb) {                                      \
        bf16x8 vf = *(const bf16x8*)&Vt[(nb * 16 + t16) * VT_STRIDE + quad * 8]; \
        acc[nb] = __builtin_amdgcn_mfma_f32_16x16x32_bf16(pf, vf, acc[nb], 0, 0, 0); \
      }                                                                     \
    }                                                                       \
    /* 7. protect LDS before next overwrite */                              \
    barrier_lgkm();                                                         \
  }

// launch_bounds(256, 3): VGPR cap ~170 — pipeline needs ~150 live regs.
// (256, 4) capped at 64 and spilled ~1.6 GB/dispatch to scratch (R2/R3).
__global__ __launch_bounds__(256, 3) void attn_fwd(
    const float* __restrict__ Q, const float* __restrict__ K,
    const float* __restrict__ V, const int* __restrict__ Mask,
    float* __restrict__ Out) {
  const int qblk = blockIdx.x;
  const int bh   = blockIdx.y;
  const int tid  = threadIdx.x;
  const int w    = tid >> 6;
  const int lane = tid & 63;
  const int t16  = lane & 15;
  const int quad = lane >> 4;

  const float* Qg = Q    + (size_t)bh * Lc_ * Dc_;
  const float* Kg = K    + (size_t)bh * Lc_ * Dc_;
  const float* Vg = V    + (size_t)bh * Lc_ * Dc_;
  const int*   Mg = Mask + (size_t)bh * Lc_ * Lc_;
  float*       Og = Out  + (size_t)bh * Lc_ * Dc_;

  const int qr0 = qblk * BR + w * 16;

  __shared__ alignas(16) unsigned short Ks[BC * KS_STRIDE];
  __shared__ alignas(16) unsigned short Vt[Dc_ * VT_STRIDE];
  __shared__ alignas(16) unsigned short Ps[4 * 16 * PS_STRIDE];

  // ---- Q fragments (A-operand), loaded once, pre-scaled ----
  bf16x8 qf[4];
  {
    const float* qrow = Qg + (size_t)(qr0 + t16) * Dc_ + quad * 8;
#pragma unroll
    for (int s = 0; s < 4; ++s) {
      const f32x4 a = *(const f32x4*)(qrow + s * 32);
      const f32x4 b = *(const f32x4*)(qrow + s * 32 + 4);
      bf16x8 f;
      f[0] = (short)f2bf(a[0] * SCALE); f[1] = (short)f2bf(a[1] * SCALE);
      f[2] = (short)f2bf(a[2] * SCALE); f[3] = (short)f2bf(a[3] * SCALE);
      f[4] = (short)f2bf(b[0] * SCALE); f[5] = (short)f2bf(b[1] * SCALE);
      f[6] = (short)f2bf(b[2] * SCALE); f[7] = (short)f2bf(b[3] * SCALE);
      qf[s] = f;
    }
  }

  f32x4 acc[8];
#pragma unroll
  for (int i = 0; i < 8; ++i) acc[i] = (f32x4)0.0f;
  float mstate[4] = {-INFINITY, -INFINITY, -INFINITY, -INFINITY};
  float lstate[4] = {0.f, 0.f, 0.f, 0.f};

  // Staging thread mappings
  const int krow = tid >> 3;   // 0..31, 8 threads/row (coalesced 64B)
  const int kcg  = tid & 7;
  const int vrow = tid & 31;
  const int vcg  = tid >> 5;

  const float* kbase_g = Kg + (size_t)krow * Dc_ + kcg * 16;
  const float* vbase_g = Vg + (size_t)vrow * Dc_ + vcg * 16;
  const int*   mbase_g = Mg + (size_t)(qr0 + quad * 4) * Lc_ + t16;

  // Prefetch registers: K/V tiles as f32x4 (distance 1), masks as NAMED
  // SCALARS in 4 buffer sets (distance 4). Runtime-indexed arrays spill
  // to scratch (R2: +1.8 GB HBM) — keep everything constant-indexed.
  f32x4 kr[4], vr[4];
  int mA0, mA1, mA2, mA3, mA4, mA5, mA6, mA7;
  int mB0, mB1, mB2, mB3, mB4, mB5, mB6, mB7;
  int mC0, mC1, mC2, mC3, mC4, mC5, mC6, mC7;
  int mD0, mD1, mD2, mD3, mD4, mD5, mD6, mD7;

  // ---- preload K/V tile 0 and mask tiles 0..3 ----
  kr[0] = *(const f32x4*)(kbase_g + 0);  kr[1] = *(const f32x4*)(kbase_g + 4);
  kr[2] = *(const f32x4*)(kbase_g + 8);  kr[3] = *(const f32x4*)(kbase_g + 12);
  vr[0] = *(const f32x4*)(vbase_g + 0);  vr[1] = *(const f32x4*)(vbase_g + 4);
  vr[2] = *(const f32x4*)(vbase_g + 8);  vr[3] = *(const f32x4*)(vbase_g + 12);
  MASK_LOAD(mA, 0 * BC)
  MASK_LOAD(mB, 1 * BC)
  MASK_LOAD(mC, 2 * BC)
  MASK_LOAD(mD, 3 * BC)

#pragma unroll 1
  for (int kb = 0; kb < Lc_; kb += 4 * BC) {
    TILE_BODY(kb,          mA)
    TILE_BODY(kb + BC,     mB)
    TILE_BODY(kb + 2 * BC, mC)
    TILE_BODY(kb + 3 * BC, mD)
  }

  // ---- epilogue: O / l ----
#pragma unroll
  for (int r = 0; r < 4; ++r) {
    const float inv = 1.0f / lstate[r];
    float* orow = Og + (size_t)(qr0 + quad * 4 + r) * Dc_ + t16;
#pragma unroll
    for (int nb = 0; nb < 8; ++nb) orow[nb * 16] = acc[nb][r] * inv;
  }
}

extern "C" void kernel_launch(void* const* d_in, const int* in_sizes, int n_in,
                              void* d_out, int out_size, void* d_ws, size_t ws_size,
                              hipStream_t stream) {
  const float* Q    = (const float*)d_in[0];
  const float* K    = (const float*)d_in[1];
  const float* V    = (const float*)d_in[2];
  const int*   Mask = (const int*)d_in[3];
  float*       Out  = (float*)d_out;
  dim3 grid(Lc_ / BR, Bc_ * Hc_);
  attn_fwd<<<grid, dim3(256), 0, stream>>>(Q, K, V, Mask, Out);
}

// Round 6
// 1106.588 us; speedup vs baseline: 1.0374x; 1.0374x over previous
//
#include <hip/hip_runtime.h>
#include <math.h>

// Problem constants (B=2, H=16, L=2048, D=128, fp32 in/out, int32 mask)
constexpr int Bc_ = 2;
constexpr int Hc_ = 16;
constexpr int Lc_ = 2048;
constexpr int Dc_ = 128;
constexpr int BR  = 64;   // Q rows per block (4 waves x 16)
constexpr int BC  = 32;   // K rows per tile
constexpr float SCALE = 0.08838834764831845f;  // 1/sqrt(128)
constexpr float NEGV  = -10000.0f;

typedef __attribute__((ext_vector_type(8))) short          bf16x8;
typedef __attribute__((ext_vector_type(8))) unsigned short u16x8;
typedef __attribute__((ext_vector_type(4))) float          f32x4;

// fp32 -> bf16 round-to-nearest-even
__device__ __forceinline__ unsigned short f2bf(float f) {
  unsigned u = __builtin_bit_cast(unsigned, f);
  return (unsigned short)((u + 0x7fffu + ((u >> 16) & 1u)) >> 16);
}

// Workgroup barrier that does NOT drain vmcnt (unlike __syncthreads).
// LDS visibility needs lgkmcnt(0) only; register-prefetch global loads
// stay in flight across the barrier.
__device__ __forceinline__ void barrier_lgkm() {
  asm volatile("s_waitcnt lgkmcnt(0)\n\ts_barrier" ::: "memory");
}

constexpr int KS_STRIDE = 136;  // K tile rows (+8 pad)
constexpr int VT_STRIDE = 72;   // V^T rows, 16B-aligned
constexpr int PS_STRIDE = 40;   // P staging rows

// ---- load 8 mask scalars for this thread's 4 rows x 2 cols at tile kbn ----
#define MASK_LOAD(MN, KBN)                                                  \
  {                                                                         \
    const int* mp = mbase_g + (KBN);                                        \
    MN##0 = mp[0 * Lc_];      MN##1 = mp[0 * Lc_ + 16];                     \
    MN##2 = mp[1 * Lc_];      MN##3 = mp[1 * Lc_ + 16];                     \
    MN##4 = mp[2 * Lc_];      MN##5 = mp[2 * Lc_ + 16];                     \
    MN##6 = mp[3 * Lc_];      MN##7 = mp[3 * Lc_ + 16];                     \
  }

// ---- softmax for one Q-row R, masks as named scalar registers ----
#define SOFTMAX_ROW(R, M0, M1)                                              \
  {                                                                         \
    float s0 = ((M0) == 0) ? NEGV : sblk[0][R];                             \
    float s1 = ((M1) == 0) ? NEGV : sblk[1][R];                             \
    float rowmax = fmaxf(s0, s1);                                           \
    rowmax = fmaxf(rowmax, __shfl_xor(rowmax, 1));                          \
    rowmax = fmaxf(rowmax, __shfl_xor(rowmax, 2));                          \
    rowmax = fmaxf(rowmax, __shfl_xor(rowmax, 4));                          \
    rowmax = fmaxf(rowmax, __shfl_xor(rowmax, 8));                          \
    const float mnew  = fmaxf(mstate[R], rowmax);                           \
    const float alpha = __expf(mstate[R] - mnew);                           \
    const float p0 = __expf(s0 - mnew);                                     \
    const float p1 = __expf(s1 - mnew);                                     \
    float rs = p0 + p1;                                                     \
    rs += __shfl_xor(rs, 1);                                                \
    rs += __shfl_xor(rs, 2);                                                \
    rs += __shfl_xor(rs, 4);                                                \
    rs += __shfl_xor(rs, 8);                                                \
    lstate[R] = lstate[R] * alpha + rs;                                     \
    mstate[R] = mnew;                                                       \
    acc[0][R] *= alpha; acc[1][R] *= alpha; acc[2][R] *= alpha;             \
    acc[3][R] *= alpha; acc[4][R] *= alpha; acc[5][R] *= alpha;             \
    acc[6][R] *= alpha; acc[7][R] *= alpha;                                 \
    unsigned short* prow = &Ps[(w * 16 + quad * 4 + (R)) * PS_STRIDE];      \
    prow[t16]      = f2bf(p0);                                              \
    prow[16 + t16] = f2bf(p1);                                              \
  }

// ---- one K-tile iteration. MC = this tile's mask buffer (consumed in
// softmax, then REFILLED with tile t+4's mask). K/V loads are issued BEFORE
// the mask loads each tile, so the in-order vmcnt retirement gives each mask
// buffer >=3 tiles of latency cover for the 536 MB uncacheable mask stream.
#define TILE_BODY(KB, MC)                                                   \
  {                                                                         \
    /* 1. stage current K regs -> LDS (bf16, row-major) */                  \
    {                                                                       \
      u16x8 p0, p1;                                                         \
      p0[0]=f2bf(kr[0][0]); p0[1]=f2bf(kr[0][1]); p0[2]=f2bf(kr[0][2]); p0[3]=f2bf(kr[0][3]); \
      p0[4]=f2bf(kr[1][0]); p0[5]=f2bf(kr[1][1]); p0[6]=f2bf(kr[1][2]); p0[7]=f2bf(kr[1][3]); \
      p1[0]=f2bf(kr[2][0]); p1[1]=f2bf(kr[2][1]); p1[2]=f2bf(kr[2][2]); p1[3]=f2bf(kr[2][3]); \
      p1[4]=f2bf(kr[3][0]); p1[5]=f2bf(kr[3][1]); p1[6]=f2bf(kr[3][2]); p1[7]=f2bf(kr[3][3]); \
      *(u16x8*)&Ks[krow * KS_STRIDE + kcg * 16]     = p0;                   \
      *(u16x8*)&Ks[krow * KS_STRIDE + kcg * 16 + 8] = p1;                   \
    }                                                                       \
    /* stage current V regs -> LDS transposed */                            \
    _Pragma("unroll")                                                       \
    for (int c4 = 0; c4 < 4; ++c4) {                                        \
      Vt[(vcg * 16 + c4 * 4 + 0) * VT_STRIDE + vrow] = f2bf(vr[c4][0]);     \
      Vt[(vcg * 16 + c4 * 4 + 1) * VT_STRIDE + vrow] = f2bf(vr[c4][1]);     \
      Vt[(vcg * 16 + c4 * 4 + 2) * VT_STRIDE + vrow] = f2bf(vr[c4][2]);     \
      Vt[(vcg * 16 + c4 * 4 + 3) * VT_STRIDE + vrow] = f2bf(vr[c4][3]);     \
    }                                                                       \
    /* 2. issue next-tile K/V loads (stay in flight across barrier) */      \
    {                                                                       \
      const int kbn = ((KB) + BC) & (Lc_ - 1);                              \
      const float* kp = kbase_g + (size_t)kbn * Dc_;                        \
      const float* vp = vbase_g + (size_t)kbn * Dc_;                        \
      kr[0] = *(const f32x4*)(kp + 0);  kr[1] = *(const f32x4*)(kp + 4);    \
      kr[2] = *(const f32x4*)(kp + 8);  kr[3] = *(const f32x4*)(kp + 12);   \
      vr[0] = *(const f32x4*)(vp + 0);  vr[1] = *(const f32x4*)(vp + 4);    \
      vr[2] = *(const f32x4*)(vp + 8);  vr[3] = *(const f32x4*)(vp + 12);   \
    }                                                                       \
    /* 3. barrier (lgkm only) */                                            \
    barrier_lgkm();                                                         \
    /* 4. S = (Q*scale) K^T */                                              \
    f32x4 sblk[2];                                                          \
    _Pragma("unroll")                                                       \
    for (int blk = 0; blk < 2; ++blk) {                                     \
      f32x4 s = (f32x4)0.0f;                                                \
      const unsigned short* kb_l = &Ks[(blk * 16 + t16) * KS_STRIDE + quad * 8]; \
      _Pragma("unroll")                                                     \
      for (int st = 0; st < 4; ++st) {                                      \
        bf16x8 bf = *(const bf16x8*)(kb_l + st * 32);                       \
        s = __builtin_amdgcn_mfma_f32_16x16x32_bf16(qf[st], bf, s, 0, 0, 0);\
      }                                                                     \
      sblk[blk] = s;                                                        \
    }                                                                       \
    /* 5. mask + online softmax (masks in registers, loaded 4 tiles ago) */ \
    SOFTMAX_ROW(0, MC##0, MC##1)                                            \
    SOFTMAX_ROW(1, MC##2, MC##3)                                            \
    SOFTMAX_ROW(2, MC##4, MC##5)                                            \
    SOFTMAX_ROW(3, MC##6, MC##7)                                            \
    /* 5.5 refill this mask buffer for tile t+4 (distance-4 prefetch) */    \
    MASK_LOAD(MC, ((KB) + 4 * BC) & (Lc_ - 1))                              \
    /* 6. O += P * V */                                                     \
    {                                                                       \
      const bf16x8 pf = *(const bf16x8*)&Ps[(w * 16 + t16) * PS_STRIDE + quad * 8]; \
      _Pragma("unroll")                                                     \
      for (int nb = 0; nb < 8; ++nb) {                                      \
        bf16x8 vf = *(const bf16x8*)&Vt[(nb * 16 + t16) * VT_STRIDE + quad * 8]; \
        acc[nb] = __builtin_amdgcn_mfma_f32_16x16x32_bf16(pf, vf, acc[nb], 0, 0, 0); \
      }                                                                     \
    }                                                                       \
    /* 7. protect LDS before next overwrite */                              \
    barrier_lgkm();                                                         \
  }

// waves_per_eu(3,3): pin BOTH min and max. launch_bounds(256,3) alone sets
// only the min -> allocator still targets 6 waves/EU (VGPR~84) and SPILLS
// the mask pipeline (~460 MB scratch traffic, R5). With max=3 the allocator
// knows pressure below 170 VGPR buys nothing and keeps the pipeline in regs.
__global__ __launch_bounds__(256)
__attribute__((amdgpu_waves_per_eu(3, 3)))
void attn_fwd(
    const float* __restrict__ Q, const float* __restrict__ K,
    const float* __restrict__ V, const int* __restrict__ Mask,
    float* __restrict__ Out) {
  const int qblk = blockIdx.x;
  const int bh   = blockIdx.y;
  const int tid  = threadIdx.x;
  const int w    = tid >> 6;
  const int lane = tid & 63;
  const int t16  = lane & 15;
  const int quad = lane >> 4;

  const float* Qg = Q    + (size_t)bh * Lc_ * Dc_;
  const float* Kg = K    + (size_t)bh * Lc_ * Dc_;
  const float* Vg = V    + (size_t)bh * Lc_ * Dc_;
  const int*   Mg = Mask + (size_t)bh * Lc_ * Lc_;
  float*       Og = Out  + (size_t)bh * Lc_ * Dc_;

  const int qr0 = qblk * BR + w * 16;

  __shared__ alignas(16) unsigned short Ks[BC * KS_STRIDE];
  __shared__ alignas(16) unsigned short Vt[Dc_ * VT_STRIDE];
  __shared__ alignas(16) unsigned short Ps[4 * 16 * PS_STRIDE];

  // ---- Q fragments (A-operand), loaded once, pre-scaled ----
  bf16x8 qf[4];
  {
    const float* qrow = Qg + (size_t)(qr0 + t16) * Dc_ + quad * 8;
#pragma unroll
    for (int s = 0; s < 4; ++s) {
      const f32x4 a = *(const f32x4*)(qrow + s * 32);
      const f32x4 b = *(const f32x4*)(qrow + s * 32 + 4);
      bf16x8 f;
      f[0] = (short)f2bf(a[0] * SCALE); f[1] = (short)f2bf(a[1] * SCALE);
      f[2] = (short)f2bf(a[2] * SCALE); f[3] = (short)f2bf(a[3] * SCALE);
      f[4] = (short)f2bf(b[0] * SCALE); f[5] = (short)f2bf(b[1] * SCALE);
      f[6] = (short)f2bf(b[2] * SCALE); f[7] = (short)f2bf(b[3] * SCALE);
      qf[s] = f;
    }
  }

  f32x4 acc[8];
#pragma unroll
  for (int i = 0; i < 8; ++i) acc[i] = (f32x4)0.0f;
  float mstate[4] = {-INFINITY, -INFINITY, -INFINITY, -INFINITY};
  float lstate[4] = {0.f, 0.f, 0.f, 0.f};

  // Staging thread mappings
  const int krow = tid >> 3;   // 0..31, 8 threads/row (coalesced 64B)
  const int kcg  = tid & 7;
  const int vrow = tid & 31;
  const int vcg  = tid >> 5;

  const float* kbase_g = Kg + (size_t)krow * Dc_ + kcg * 16;
  const float* vbase_g = Vg + (size_t)vrow * Dc_ + vcg * 16;
  const int*   mbase_g = Mg + (size_t)(qr0 + quad * 4) * Lc_ + t16;

  // Prefetch registers: K/V tiles as f32x4 (distance 1), masks as NAMED
  // SCALARS in 4 buffer sets (distance 4). Runtime-indexed arrays spill
  // to scratch (R2: +1.8 GB HBM) — keep everything constant-indexed.
  f32x4 kr[4], vr[4];
  int mA0, mA1, mA2, mA3, mA4, mA5, mA6, mA7;
  int mB0, mB1, mB2, mB3, mB4, mB5, mB6, mB7;
  int mC0, mC1, mC2, mC3, mC4, mC5, mC6, mC7;
  int mD0, mD1, mD2, mD3, mD4, mD5, mD6, mD7;

  // ---- preload K/V tile 0 and mask tiles 0..3 ----
  kr[0] = *(const f32x4*)(kbase_g + 0);  kr[1] = *(const f32x4*)(kbase_g + 4);
  kr[2] = *(const f32x4*)(kbase_g + 8);  kr[3] = *(const f32x4*)(kbase_g + 12);
  vr[0] = *(const f32x4*)(vbase_g + 0);  vr[1] = *(const f32x4*)(vbase_g + 4);
  vr[2] = *(const f32x4*)(vbase_g + 8);  vr[3] = *(const f32x4*)(vbase_g + 12);
  MASK_LOAD(mA, 0 * BC)
  MASK_LOAD(mB, 1 * BC)
  MASK_LOAD(mC, 2 * BC)
  MASK_LOAD(mD, 3 * BC)

#pragma unroll 1
  for (int kb = 0; kb < Lc_; kb += 4 * BC) {
    TILE_BODY(kb,          mA)
    TILE_BODY(kb + BC,     mB)
    TILE_BODY(kb + 2 * BC, mC)
    TILE_BODY(kb + 3 * BC, mD)
  }

  // ---- epilogue: O / l ----
#pragma unroll
  for (int r = 0; r < 4; ++r) {
    const float inv = 1.0f / lstate[r];
    float* orow = Og + (size_t)(qr0 + quad * 4 + r) * Dc_ + t16;
#pragma unroll
    for (int nb = 0; nb < 8; ++nb) orow[nb * 16] = acc[nb][r] * inv;
  }
}

extern "C" void kernel_launch(void* const* d_in, const int* in_sizes, int n_in,
                              void* d_out, int out_size, void* d_ws, size_t ws_size,
                              hipStream_t stream) {
  const float* Q    = (const float*)d_in[0];
  const float* K    = (const float*)d_in[1];
  const float* V    = (const float*)d_in[2];
  const int*   Mask = (const int*)d_in[3];
  float*       Out  = (float*)d_out;
  dim3 grid(Lc_ / BR, Bc_ * Hc_);
  attn_fwd<<<grid, dim3(256), 0, stream>>>(Q, K, V, Mask, Out);
}

// Round 7
// 1102.206 us; speedup vs baseline: 1.0415x; 1.0040x over previous
//
#include <hip/hip_runtime.h>
#include <math.h>

// Problem constants (B=2, H=16, L=2048, D=128, fp32 in/out, int32 mask)
constexpr int Bc_ = 2;
constexpr int Hc_ = 16;
constexpr int Lc_ = 2048;
constexpr int Dc_ = 128;
constexpr int BR  = 64;   // Q rows per block (4 waves x 16)
constexpr int BC  = 32;   // K rows per tile
constexpr float SCALE = 0.08838834764831845f;  // 1/sqrt(128)
constexpr float NEGV  = -10000.0f;

typedef __attribute__((ext_vector_type(8))) short          bf16x8;
typedef __attribute__((ext_vector_type(8))) unsigned short u16x8;
typedef __attribute__((ext_vector_type(4))) float          f32x4;
typedef __attribute__((ext_vector_type(4))) int            i32x4;

// fp32 -> bf16 round-to-nearest-even
__device__ __forceinline__ unsigned short f2bf(float f) {
  unsigned u = __builtin_bit_cast(unsigned, f);
  return (unsigned short)((u + 0x7fffu + ((u >> 16) & 1u)) >> 16);
}

// Workgroup barrier that does NOT drain vmcnt (unlike __syncthreads).
// LDS visibility needs lgkmcnt(0) only; register-prefetch global loads
// stay in flight across the barrier.
__device__ __forceinline__ void barrier_lgkm() {
  asm volatile("s_waitcnt lgkmcnt(0)\n\ts_barrier" ::: "memory");
}

constexpr int KS_STRIDE = 136;  // K tile rows (+8 pad)
constexpr int VT_STRIDE = 72;   // V^T rows, 16B-aligned
constexpr int PS_STRIDE = 40;   // P staging rows
constexpr int MS_STRIDE = 65;   // mask LDS col-major [col][row], row-dim padded 64->65
                                // (bank = (col+row)%32 -> <=2-way on both access patterns)

// ---- softmax for one Q-row R; M0/M1 are mask ints (from LDS) ----
#define SOFTMAX_ROW(R, M0, M1)                                              \
  {                                                                         \
    float s0 = ((M0) == 0) ? NEGV : sblk[0][R];                             \
    float s1 = ((M1) == 0) ? NEGV : sblk[1][R];                             \
    float rowmax = fmaxf(s0, s1);                                           \
    rowmax = fmaxf(rowmax, __shfl_xor(rowmax, 1));                          \
    rowmax = fmaxf(rowmax, __shfl_xor(rowmax, 2));                          \
    rowmax = fmaxf(rowmax, __shfl_xor(rowmax, 4));                          \
    rowmax = fmaxf(rowmax, __shfl_xor(rowmax, 8));                          \
    const float mnew  = fmaxf(mstate[R], rowmax);                           \
    const float alpha = __expf(mstate[R] - mnew);                           \
    const float p0 = __expf(s0 - mnew);                                     \
    const float p1 = __expf(s1 - mnew);                                     \
    float rs = p0 + p1;                                                     \
    rs += __shfl_xor(rs, 1);                                                \
    rs += __shfl_xor(rs, 2);                                                \
    rs += __shfl_xor(rs, 4);                                                \
    rs += __shfl_xor(rs, 8);                                                \
    lstate[R] = lstate[R] * alpha + rs;                                     \
    mstate[R] = mnew;                                                       \
    acc[0][R] *= alpha; acc[1][R] *= alpha; acc[2][R] *= alpha;             \
    acc[3][R] *= alpha; acc[4][R] *= alpha; acc[5][R] *= alpha;             \
    acc[6][R] *= alpha; acc[7][R] *= alpha;                                 \
    unsigned short* prow = &Ps[(w * 16 + quad * 4 + (R)) * PS_STRIDE];      \
    prow[t16]      = f2bf(p0);                                              \
    prow[16 + t16] = f2bf(p1);                                              \
  }

// ---- one K-tile iteration, tile index t = KB/BC.
// MSa/MSb: register set holding mask tile t+1 (2x int4/thread). It is staged
// to LDS buf WB here, then refilled with tile t+3 (consumed 2 bodies later ->
// the vmcnt wait before that ds_write sits ~2 tile periods (~1760 cyc) after
// issue, covering the ~900 cyc HBM miss of the uncacheable mask stream).
// Softmax reads tile t from LDS buf RB (written @ body t-1, barrier between).
#define TILE_BODY(KB, MSa, MSb, WB, RB)                                     \
  {                                                                         \
    /* 1. stage K/V regs -> LDS; stage mask regs (tile t+1) -> Msk[WB] */   \
    {                                                                       \
      u16x8 p0, p1;                                                         \
      p0[0]=f2bf(kr[0][0]); p0[1]=f2bf(kr[0][1]); p0[2]=f2bf(kr[0][2]); p0[3]=f2bf(kr[0][3]); \
      p0[4]=f2bf(kr[1][0]); p0[5]=f2bf(kr[1][1]); p0[6]=f2bf(kr[1][2]); p0[7]=f2bf(kr[1][3]); \
      p1[0]=f2bf(kr[2][0]); p1[1]=f2bf(kr[2][1]); p1[2]=f2bf(kr[2][2]); p1[3]=f2bf(kr[2][3]); \
      p1[4]=f2bf(kr[3][0]); p1[5]=f2bf(kr[3][1]); p1[6]=f2bf(kr[3][2]); p1[7]=f2bf(kr[3][3]); \
      *(u16x8*)&Ks[krow * KS_STRIDE + kcg * 16]     = p0;                   \
      *(u16x8*)&Ks[krow * KS_STRIDE + kcg * 16 + 8] = p1;                   \
    }                                                                       \
    _Pragma("unroll")                                                       \
    for (int c4 = 0; c4 < 4; ++c4) {                                        \
      Vt[(vcg * 16 + c4 * 4 + 0) * VT_STRIDE + vrow] = f2bf(vr[c4][0]);     \
      Vt[(vcg * 16 + c4 * 4 + 1) * VT_STRIDE + vrow] = f2bf(vr[c4][1]);     \
      Vt[(vcg * 16 + c4 * 4 + 2) * VT_STRIDE + vrow] = f2bf(vr[c4][2]);     \
      Vt[(vcg * 16 + c4 * 4 + 3) * VT_STRIDE + vrow] = f2bf(vr[c4][3]);     \
    }                                                                       \
    {                                                                       \
      int* mwv = &Msk[WB][(mcol0 + 0) * MS_STRIDE + mrow];                  \
      mwv[0 * MS_STRIDE] = MSa[0]; mwv[1 * MS_STRIDE] = MSa[1];             \
      mwv[2 * MS_STRIDE] = MSa[2]; mwv[3 * MS_STRIDE] = MSa[3];             \
      mwv[4 * MS_STRIDE] = MSb[0]; mwv[5 * MS_STRIDE] = MSb[1];             \
      mwv[6 * MS_STRIDE] = MSb[2]; mwv[7 * MS_STRIDE] = MSb[3];             \
    }                                                                       \
    /* 2. issue K/V loads (t+1) and mask loads (t+3); all stay in flight */ \
    {                                                                       \
      const int kbn = ((KB) + BC) & (Lc_ - 1);                              \
      const float* kp = kbase_g + (size_t)kbn * Dc_;                        \
      const float* vp = vbase_g + (size_t)kbn * Dc_;                        \
      kr[0] = *(const f32x4*)(kp + 0);  kr[1] = *(const f32x4*)(kp + 4);    \
      kr[2] = *(const f32x4*)(kp + 8);  kr[3] = *(const f32x4*)(kp + 12);   \
      vr[0] = *(const f32x4*)(vp + 0);  vr[1] = *(const f32x4*)(vp + 4);    \
      vr[2] = *(const f32x4*)(vp + 8);  vr[3] = *(const f32x4*)(vp + 12);   \
      const int kbm = ((KB) + 3 * BC) & (Lc_ - 1);                          \
      MSa = *(const i32x4*)(mload_g + kbm);                                 \
      MSb = *(const i32x4*)(mload_g + kbm + 4);                             \
    }                                                                       \
    /* 3. barrier (lgkm only; vmem prefetch stays outstanding) */           \
    barrier_lgkm();                                                         \
    /* 4. S = (Q*scale) K^T */                                              \
    f32x4 sblk[2];                                                          \
    _Pragma("unroll")                                                       \
    for (int blk = 0; blk < 2; ++blk) {                                     \
      f32x4 s = (f32x4)0.0f;                                                \
      const unsigned short* kb_l = &Ks[(blk * 16 + t16) * KS_STRIDE + quad * 8]; \
      _Pragma("unroll")                                                     \
      for (int st = 0; st < 4; ++st) {                                      \
        bf16x8 bf = *(const bf16x8*)(kb_l + st * 32);                       \
        s = __builtin_amdgcn_mfma_f32_16x16x32_bf16(qf[st], bf, s, 0, 0, 0);\
      }                                                                     \
      sblk[blk] = s;                                                        \
    }                                                                       \
    /* 5. mask (from LDS buf RB) + online softmax */                        \
    {                                                                       \
      const int* mrd0 = &Msk[RB][t16 * MS_STRIDE + mrow_rd];                \
      const int* mrd1 = mrd0 + 16 * MS_STRIDE;                              \
      SOFTMAX_ROW(0, mrd0[0], mrd1[0])                                      \
      SOFTMAX_ROW(1, mrd0[1], mrd1[1])                                      \
      SOFTMAX_ROW(2, mrd0[2], mrd1[2])                                      \
      SOFTMAX_ROW(3, mrd0[3], mrd1[3])                                      \
    }                                                                       \
    /* 6. O += P * V */                                                     \
    {                                                                       \
      const bf16x8 pf = *(const bf16x8*)&Ps[(w * 16 + t16) * PS_STRIDE + quad * 8]; \
      _Pragma("unroll")                                                     \
      for (int nb = 0; nb < 8; ++nb) {                                      \
        bf16x8 vf = *(const bf16x8*)&Vt[(nb * 16 + t16) * VT_STRIDE + quad * 8]; \
        acc[nb] = __builtin_amdgcn_mfma_f32_16x16x32_bf16(pf, vf, acc[nb], 0, 0, 0); \
      }                                                                     \
    }                                                                       \
    /* 7. protect LDS before next overwrite */                              \
    barrier_lgkm();                                                         \
  }

// (256,3): VGPR cap ~170. Register footprint matches R4's proven 80-reg fit:
// mask pipeline depth lives in LDS, not registers (R5/R6: 4 register buffers
// -> allocator spilled ~300-460 MB/dispatch regardless of occupancy hints).
__global__ __launch_bounds__(256, 3) void attn_fwd(
    const float* __restrict__ Q, const float* __restrict__ K,
    const float* __restrict__ V, const int* __restrict__ Mask,
    float* __restrict__ Out) {
  const int qblk = blockIdx.x;
  const int bh   = blockIdx.y;
  const int tid  = threadIdx.x;
  const int w    = tid >> 6;
  const int lane = tid & 63;
  const int t16  = lane & 15;
  const int quad = lane >> 4;

  const float* Qg = Q    + (size_t)bh * Lc_ * Dc_;
  const float* Kg = K    + (size_t)bh * Lc_ * Dc_;
  const float* Vg = V    + (size_t)bh * Lc_ * Dc_;
  const int*   Mg = Mask + (size_t)bh * Lc_ * Lc_;
  float*       Og = Out  + (size_t)bh * Lc_ * Dc_;

  const int qr0 = qblk * BR + w * 16;

  __shared__ alignas(16) unsigned short Ks[BC * KS_STRIDE];
  __shared__ alignas(16) unsigned short Vt[Dc_ * VT_STRIDE];
  __shared__ alignas(16) unsigned short Ps[4 * 16 * PS_STRIDE];
  __shared__ alignas(16) int Msk[2][BC * MS_STRIDE];   // 2 x 8.3 KB mask tiles

  // ---- Q fragments (A-operand), loaded once, pre-scaled ----
  bf16x8 qf[4];
  {
    const float* qrow = Qg + (size_t)(qr0 + t16) * Dc_ + quad * 8;
#pragma unroll
    for (int s = 0; s < 4; ++s) {
      const f32x4 a = *(const f32x4*)(qrow + s * 32);
      const f32x4 b = *(const f32x4*)(qrow + s * 32 + 4);
      bf16x8 f;
      f[0] = (short)f2bf(a[0] * SCALE); f[1] = (short)f2bf(a[1] * SCALE);
      f[2] = (short)f2bf(a[2] * SCALE); f[3] = (short)f2bf(a[3] * SCALE);
      f[4] = (short)f2bf(b[0] * SCALE); f[5] = (short)f2bf(b[1] * SCALE);
      f[6] = (short)f2bf(b[2] * SCALE); f[7] = (short)f2bf(b[3] * SCALE);
      qf[s] = f;
    }
  }

  f32x4 acc[8];
#pragma unroll
  for (int i = 0; i < 8; ++i) acc[i] = (f32x4)0.0f;
  float mstate[4] = {-INFINITY, -INFINITY, -INFINITY, -INFINITY};
  float lstate[4] = {0.f, 0.f, 0.f, 0.f};

  // Staging thread mappings
  const int krow = tid >> 3;           // K: 0..31, 8 threads/row
  const int kcg  = tid & 7;
  const int vrow = tid & 31;           // V: k index
  const int vcg  = tid >> 5;
  const int mrow    = tid >> 2;        // mask stage: row 0..63
  const int mcol0   = (tid & 3) * 8;   // mask stage: first of 8 cols
  const int mrow_rd = w * 16 + quad * 4;  // mask read: this thread's rows

  const float* kbase_g = Kg + (size_t)krow * Dc_ + kcg * 16;
  const float* vbase_g = Vg + (size_t)vrow * Dc_ + vcg * 16;
  const int*   mload_g = Mg + (size_t)(qblk * BR + mrow) * Lc_ + mcol0;

  // K/V prefetch regs (distance 1, L2-resident) + two mask int4-pair sets
  f32x4 kr[4], vr[4];
  i32x4 MAa, MAb, MBa, MBb;

  // ---- preamble: mask tile 0 -> Msk[0] direct; tiles 1,2 -> reg sets ----
  {
    i32x4 t0a = *(const i32x4*)(mload_g + 0);
    i32x4 t0b = *(const i32x4*)(mload_g + 4);
    int* mwv = &Msk[0][mcol0 * MS_STRIDE + mrow];
    mwv[0 * MS_STRIDE] = t0a[0]; mwv[1 * MS_STRIDE] = t0a[1];
    mwv[2 * MS_STRIDE] = t0a[2]; mwv[3 * MS_STRIDE] = t0a[3];
    mwv[4 * MS_STRIDE] = t0b[0]; mwv[5 * MS_STRIDE] = t0b[1];
    mwv[6 * MS_STRIDE] = t0b[2]; mwv[7 * MS_STRIDE] = t0b[3];
  }
  MAa = *(const i32x4*)(mload_g + BC);      MAb = *(const i32x4*)(mload_g + BC + 4);
  MBa = *(const i32x4*)(mload_g + 2 * BC);  MBb = *(const i32x4*)(mload_g + 2 * BC + 4);
  kr[0] = *(const f32x4*)(kbase_g + 0);  kr[1] = *(const f32x4*)(kbase_g + 4);
  kr[2] = *(const f32x4*)(kbase_g + 8);  kr[3] = *(const f32x4*)(kbase_g + 12);
  vr[0] = *(const f32x4*)(vbase_g + 0);  vr[1] = *(const f32x4*)(vbase_g + 4);
  vr[2] = *(const f32x4*)(vbase_g + 8);  vr[3] = *(const f32x4*)(vbase_g + 12);

#pragma unroll 1
  for (int kb = 0; kb < Lc_; kb += 2 * BC) {
    TILE_BODY(kb,      MAa, MAb, 1, 0)   // even tile: stages t+1 -> buf1, reads buf0
    TILE_BODY(kb + BC, MBa, MBb, 0, 1)   // odd tile:  stages t+1 -> buf0, reads buf1
  }

  // ---- epilogue: O / l ----
#pragma unroll
  for (int r = 0; r < 4; ++r) {
    const float inv = 1.0f / lstate[r];
    float* orow = Og + (size_t)(qr0 + quad * 4 + r) * Dc_ + t16;
#pragma unroll
    for (int nb = 0; nb < 8; ++nb) orow[nb * 16] = acc[nb][r] * inv;
  }
}

extern "C" void kernel_launch(void* const* d_in, const int* in_sizes, int n_in,
                              void* d_out, int out_size, void* d_ws, size_t ws_size,
                              hipStream_t stream) {
  const float* Q    = (const float*)d_in[0];
  const float* K    = (const float*)d_in[1];
  const float* V    = (const float*)d_in[2];
  const int*   Mask = (const int*)d_in[3];
  float*       Out  = (float*)d_out;
  dim3 grid(Lc_ / BR, Bc_ * Hc_);
  attn_fwd<<<grid, dim3(256), 0, stream>>>(Q, K, V, Mask, Out);
}

// Round 8
// 965.638 us; speedup vs baseline: 1.1888x; 1.1414x over previous
//
#include <hip/hip_runtime.h>
#include <math.h>

// Problem constants (B=2, H=16, L=2048, D=128, fp32 in/out, int32 mask)
constexpr int Bc_ = 2;
constexpr int Hc_ = 16;
constexpr int Lc_ = 2048;
constexpr int Dc_ = 128;
constexpr int BR  = 64;   // Q rows per block (4 waves x 16)
constexpr int BC  = 32;   // K rows per tile
constexpr float SCALE = 0.08838834764831845f;  // 1/sqrt(128)
constexpr float NEGV  = -10000.0f;

typedef __attribute__((ext_vector_type(8))) short          bf16x8;
typedef __attribute__((ext_vector_type(8))) unsigned short u16x8;
typedef __attribute__((ext_vector_type(4))) float          f32x4;

// fp32 -> bf16 round-to-nearest-even
__device__ __forceinline__ unsigned short f2bf(float f) {
  unsigned u = __builtin_bit_cast(unsigned, f);
  return (unsigned short)((u + 0x7fffu + ((u >> 16) & 1u)) >> 16);
}

// Workgroup barrier that does NOT drain vmcnt (unlike __syncthreads).
// LDS visibility needs lgkmcnt(0) only; in-flight global loads / DMAs
// survive the barrier.
__device__ __forceinline__ void barrier_lgkm() {
  asm volatile("s_waitcnt lgkmcnt(0)\n\ts_barrier" ::: "memory");
}

// Async global->LDS DMA, 16 B/lane. Zero VGPR cost: no return registers.
// LDS dest is wave-uniform base + lane*16; global address is per-lane.
__device__ __forceinline__ void gld_lds16(const int* g, int* l) {
  __builtin_amdgcn_global_load_lds(
      (const __attribute__((address_space(1))) void*)g,
      (__attribute__((address_space(3))) void*)l, 16, 0, 0);
}

constexpr int KS_STRIDE = 136;  // K tile rows (+8 pad)
constexpr int VT_STRIDE = 72;   // V^T rows, 16B-aligned
constexpr int PS_STRIDE = 40;   // P staging rows

// ---- softmax for one Q-row R; M0/M1 are mask ints (read from LDS) ----
#define SOFTMAX_ROW(R, M0, M1)                                              \
  {                                                                         \
    float s0 = ((M0) == 0) ? NEGV : sblk[0][R];                             \
    float s1 = ((M1) == 0) ? NEGV : sblk[1][R];                             \
    float rowmax = fmaxf(s0, s1);                                           \
    rowmax = fmaxf(rowmax, __shfl_xor(rowmax, 1));                          \
    rowmax = fmaxf(rowmax, __shfl_xor(rowmax, 2));                          \
    rowmax = fmaxf(rowmax, __shfl_xor(rowmax, 4));                          \
    rowmax = fmaxf(rowmax, __shfl_xor(rowmax, 8));                          \
    const float mnew  = fmaxf(mstate[R], rowmax);                           \
    const float alpha = __expf(mstate[R] - mnew);                           \
    const float p0 = __expf(s0 - mnew);                                     \
    const float p1 = __expf(s1 - mnew);                                     \
    float rs = p0 + p1;                                                     \
    rs += __shfl_xor(rs, 1);                                                \
    rs += __shfl_xor(rs, 2);                                                \
    rs += __shfl_xor(rs, 4);                                                \
    rs += __shfl_xor(rs, 8);                                                \
    lstate[R] = lstate[R] * alpha + rs;                                     \
    mstate[R] = mnew;                                                       \
    acc[0][R] *= alpha; acc[1][R] *= alpha; acc[2][R] *= alpha;             \
    acc[3][R] *= alpha; acc[4][R] *= alpha; acc[5][R] *= alpha;             \
    acc[6][R] *= alpha; acc[7][R] *= alpha;                                 \
    unsigned short* prow = &Ps[(w * 16 + quad * 4 + (R)) * PS_STRIDE];      \
    prow[t16]      = f2bf(p0);                                              \
    prow[16 + t16] = f2bf(p1);                                              \
  }

// ---- one K-tile iteration, tile t = KB/BC, BUF = t&1.
// Mask pipeline: tile t's mask sits in Msk[BUF] (DMA'd 2 bodies ago, ~1600+
// cycles of cover for the ~900-cyc HBM miss). After the softmax consumes it,
// the same buffer is re-targeted with tile t+2's DMA. Wave w DMAs exactly
// the 16 rows wave w reads -> wave-private, no barrier needed for Msk.
#define TILE_BODY(KB, BUF)                                                  \
  {                                                                         \
    /* 1. stage current K/V regs -> LDS (bf16) */                           \
    {                                                                       \
      u16x8 p0, p1;                                                         \
      p0[0]=f2bf(kr[0][0]); p0[1]=f2bf(kr[0][1]); p0[2]=f2bf(kr[0][2]); p0[3]=f2bf(kr[0][3]); \
      p0[4]=f2bf(kr[1][0]); p0[5]=f2bf(kr[1][1]); p0[6]=f2bf(kr[1][2]); p0[7]=f2bf(kr[1][3]); \
      p1[0]=f2bf(kr[2][0]); p1[1]=f2bf(kr[2][1]); p1[2]=f2bf(kr[2][2]); p1[3]=f2bf(kr[2][3]); \
      p1[4]=f2bf(kr[3][0]); p1[5]=f2bf(kr[3][1]); p1[6]=f2bf(kr[3][2]); p1[7]=f2bf(kr[3][3]); \
      *(u16x8*)&Ks[krow * KS_STRIDE + kcg * 16]     = p0;                   \
      *(u16x8*)&Ks[krow * KS_STRIDE + kcg * 16 + 8] = p1;                   \
    }                                                                       \
    _Pragma("unroll")                                                       \
    for (int c4 = 0; c4 < 4; ++c4) {                                        \
      Vt[(vcg * 16 + c4 * 4 + 0) * VT_STRIDE + vrow] = f2bf(vr[c4][0]);     \
      Vt[(vcg * 16 + c4 * 4 + 1) * VT_STRIDE + vrow] = f2bf(vr[c4][1]);     \
      Vt[(vcg * 16 + c4 * 4 + 2) * VT_STRIDE + vrow] = f2bf(vr[c4][2]);     \
      Vt[(vcg * 16 + c4 * 4 + 3) * VT_STRIDE + vrow] = f2bf(vr[c4][3]);     \
    }                                                                       \
    /* 2. issue next-tile K/V loads (stay in flight across barrier) */      \
    {                                                                       \
      const int kbn = ((KB) + BC) & (Lc_ - 1);                              \
      const float* kp = kbase_g + (size_t)kbn * Dc_;                        \
      const float* vp = vbase_g + (size_t)kbn * Dc_;                        \
      kr[0] = *(const f32x4*)(kp + 0);  kr[1] = *(const f32x4*)(kp + 4);    \
      kr[2] = *(const f32x4*)(kp + 8);  kr[3] = *(const f32x4*)(kp + 12);   \
      vr[0] = *(const f32x4*)(vp + 0);  vr[1] = *(const f32x4*)(vp + 4);    \
      vr[2] = *(const f32x4*)(vp + 8);  vr[3] = *(const f32x4*)(vp + 12);   \
    }                                                                       \
    /* 3. barrier (lgkm only; vmem prefetch + mask DMA stay outstanding) */ \
    barrier_lgkm();                                                         \
    /* 4. S = (Q*scale) K^T */                                              \
    f32x4 sblk[2];                                                          \
    _Pragma("unroll")                                                       \
    for (int blk = 0; blk < 2; ++blk) {                                     \
      f32x4 s = (f32x4)0.0f;                                                \
      const unsigned short* kb_l = &Ks[(blk * 16 + t16) * KS_STRIDE + quad * 8]; \
      _Pragma("unroll")                                                     \
      for (int st = 0; st < 4; ++st) {                                      \
        bf16x8 bf = *(const bf16x8*)(kb_l + st * 32);                       \
        s = __builtin_amdgcn_mfma_f32_16x16x32_bf16(qf[st], bf, s, 0, 0, 0);\
      }                                                                     \
      sblk[blk] = s;                                                        \
    }                                                                       \
    /* 5. safety: force mask DMA of tile t complete. At most 10 younger    \
       vmem ops (8 K/V + 2 DMA) are legitimately in flight -> vmcnt(10)    \
       never stalls them, but forces anything older (this tile's DMA). */   \
    asm volatile("s_waitcnt vmcnt(10)" ::: "memory");                       \
    {                                                                       \
      const int* mrd = &Msk[BUF][mrow_rd * 32 + t16];                       \
      SOFTMAX_ROW(0, mrd[0 * 32], mrd[0 * 32 + 16])                         \
      SOFTMAX_ROW(1, mrd[1 * 32], mrd[1 * 32 + 16])                         \
      SOFTMAX_ROW(2, mrd[2 * 32], mrd[2 * 32 + 16])                         \
      SOFTMAX_ROW(3, mrd[3 * 32], mrd[3 * 32 + 16])                         \
    }                                                                       \
    /* 6. re-target this buffer: DMA mask tile t+2 (zero VGPR cost) */      \
    {                                                                       \
      const int kbt = ((KB) + 2 * BC) & (Lc_ - 1);                          \
      gld_lds16(mdma_g + kbt,           &Msk[BUF][(w * 16 + 0) * 32]);      \
      gld_lds16(mdma_g + kbt + 8 * Lc_, &Msk[BUF][(w * 16 + 8) * 32]);      \
    }                                                                       \
    /* 7. O += P * V */                                                     \
    {                                                                       \
      const bf16x8 pf = *(const bf16x8*)&Ps[(w * 16 + t16) * PS_STRIDE + quad * 8]; \
      _Pragma("unroll")                                                     \
      for (int nb = 0; nb < 8; ++nb) {                                      \
        bf16x8 vf = *(const bf16x8*)&Vt[(nb * 16 + t16) * VT_STRIDE + quad * 8]; \
        acc[nb] = __builtin_amdgcn_mfma_f32_16x16x32_bf16(pf, vf, acc[nb], 0, 0, 0); \
      }                                                                     \
    }                                                                       \
    /* 8. protect K/V/P LDS before next overwrite */                        \
    barrier_lgkm();                                                         \
  }

// Register budget: the allocator pins at 84 VGPR (6 waves/EU target) no
// matter what hints we give (R5/R6/R7). This build fits UNDER it: mask
// pipeline is global_load_lds DMA (no registers), K/V distance-1 like the
// proven 80-reg R4 build.
__global__ __launch_bounds__(256, 3) void attn_fwd(
    const float* __restrict__ Q, const float* __restrict__ K,
    const float* __restrict__ V, const int* __restrict__ Mask,
    float* __restrict__ Out) {
  const int qblk = blockIdx.x;
  const int bh   = blockIdx.y;
  const int tid  = threadIdx.x;
  const int w    = tid >> 6;
  const int lane = tid & 63;
  const int t16  = lane & 15;
  const int quad = lane >> 4;

  const float* Qg = Q    + (size_t)bh * Lc_ * Dc_;
  const float* Kg = K    + (size_t)bh * Lc_ * Dc_;
  const float* Vg = V    + (size_t)bh * Lc_ * Dc_;
  const int*   Mg = Mask + (size_t)bh * Lc_ * Lc_;
  float*       Og = Out  + (size_t)bh * Lc_ * Dc_;

  const int qr0 = qblk * BR + w * 16;

  __shared__ alignas(16) unsigned short Ks[BC * KS_STRIDE];      // 8.5 KB
  __shared__ alignas(16) unsigned short Vt[Dc_ * VT_STRIDE];     // 18 KB
  __shared__ alignas(16) unsigned short Ps[4 * 16 * PS_STRIDE];  // 5 KB
  __shared__ alignas(16) int Msk[2][BR * BC];                    // 16 KB ring

  // ---- Q fragments (A-operand), loaded once, pre-scaled ----
  bf16x8 qf[4];
  {
    const float* qrow = Qg + (size_t)(qr0 + t16) * Dc_ + quad * 8;
#pragma unroll
    for (int s = 0; s < 4; ++s) {
      const f32x4 a = *(const f32x4*)(qrow + s * 32);
      const f32x4 b = *(const f32x4*)(qrow + s * 32 + 4);
      bf16x8 f;
      f[0] = (short)f2bf(a[0] * SCALE); f[1] = (short)f2bf(a[1] * SCALE);
      f[2] = (short)f2bf(a[2] * SCALE); f[3] = (short)f2bf(a[3] * SCALE);
      f[4] = (short)f2bf(b[0] * SCALE); f[5] = (short)f2bf(b[1] * SCALE);
      f[6] = (short)f2bf(b[2] * SCALE); f[7] = (short)f2bf(b[3] * SCALE);
      qf[s] = f;
    }
  }

  f32x4 acc[8];
#pragma unroll
  for (int i = 0; i < 8; ++i) acc[i] = (f32x4)0.0f;
  float mstate[4] = {-INFINITY, -INFINITY, -INFINITY, -INFINITY};
  float lstate[4] = {0.f, 0.f, 0.f, 0.f};

  // Staging thread mappings
  const int krow = tid >> 3;           // K: 0..31, 8 threads/row
  const int kcg  = tid & 7;
  const int vrow = tid & 31;           // V: k index
  const int vcg  = tid >> 5;
  const int mrow_rd = w * 16 + quad * 4;  // mask read rows (wave-private)

  const float* kbase_g = Kg + (size_t)krow * Dc_ + kcg * 16;
  const float* vbase_g = Vg + (size_t)vrow * Dc_ + vcg * 16;
  // Mask DMA: lane i covers row (i>>3), int-cols (i&7)*4..+3 of the tile;
  // instr h adds 8 rows. LDS dest base+16B*lane lands row-major [row][col].
  const int* mdma_g = Mg + (size_t)(qblk * BR + w * 16 + (lane >> 3)) * Lc_
                         + (lane & 7) * 4;

  // K/V prefetch regs (distance 1, L2-resident)
  f32x4 kr[4], vr[4];

  // ---- preamble: DMA mask tiles 0,1 into the ring; load K/V tile 0 ----
  gld_lds16(mdma_g + 0,            &Msk[0][(w * 16 + 0) * 32]);
  gld_lds16(mdma_g + 8 * Lc_,      &Msk[0][(w * 16 + 8) * 32]);
  gld_lds16(mdma_g + BC,           &Msk[1][(w * 16 + 0) * 32]);
  gld_lds16(mdma_g + BC + 8 * Lc_, &Msk[1][(w * 16 + 8) * 32]);
  kr[0] = *(const f32x4*)(kbase_g + 0);  kr[1] = *(const f32x4*)(kbase_g + 4);
  kr[2] = *(const f32x4*)(kbase_g + 8);  kr[3] = *(const f32x4*)(kbase_g + 12);
  vr[0] = *(const f32x4*)(vbase_g + 0);  vr[1] = *(const f32x4*)(vbase_g + 4);
  vr[2] = *(const f32x4*)(vbase_g + 8);  vr[3] = *(const f32x4*)(vbase_g + 12);

#pragma unroll 1
  for (int kb = 0; kb < Lc_; kb += 2 * BC) {
    TILE_BODY(kb,      0)
    TILE_BODY(kb + BC, 1)
  }

  // ---- epilogue: O / l ----
#pragma unroll
  for (int r = 0; r < 4; ++r) {
    const float inv = 1.0f / lstate[r];
    float* orow = Og + (size_t)(qr0 + quad * 4 + r) * Dc_ + t16;
#pragma unroll
    for (int nb = 0; nb < 8; ++nb) orow[nb * 16] = acc[nb][r] * inv;
  }
}

extern "C" void kernel_launch(void* const* d_in, const int* in_sizes, int n_in,
                              void* d_out, int out_size, void* d_ws, size_t ws_size,
                              hipStream_t stream) {
  const float* Q    = (const float*)d_in[0];
  const float* K    = (const float*)d_in[1];
  const float* V    = (const float*)d_in[2];
  const int*   Mask = (const int*)d_in[3];
  float*       Out  = (float*)d_out;
  dim3 grid(Lc_ / BR, Bc_ * Hc_);
  attn_fwd<<<grid, dim3(256), 0, stream>>>(Q, K, V, Mask, Out);
}